// Round 11
// baseline (322.218 us; speedup 1.0000x reference)
//
#include <hip/hip_runtime.h>
#include <hip/hip_cooperative_groups.h>
#include <hip/hip_bf16.h>
#include <cstddef>
#include <cstdint>

// GAT layer: B=8, N=2048, C_IN=128, C_OUT=64, fp32 in/out.
//
// Rank-1 scores: e[b,i,j] = lrelu(s1[b,i] + s2[b,j]); mask = adj>0 | diag.
// Unnormalized softmax (shift-invariant); p = max(E1*E2, F1*F2) with
// E=exp2(z·log2e), F=exp2(0.01z·log2e) per row — inner loop has NO exp.
// l row-sum via extra MFMA against all-ones B fragment.
//
// ROUND-11: r9 (best, 112.4) with ONE structural change: prep+attn fused into
// a single cooperative kernel (512 blocks x 512 thr, 66 KB LDS -> exactly
// 2 blocks/CU = 512 co-resident) with this_grid().sync() between phases —
// removes the prep->attn dispatch boundary + drain. Phase A = r9 prep
// (same 4-rows/wave proj, flat Wl; 4 mask rows/block); Phase C = r9 attn
// verbatim. __threadfence() around the grid sync for cross-XCD visibility
// (per-XCD L2s non-coherent). Fallback: if cooperative launch fails, run the
// two-kernel r9 path (deterministic).
//
// ws budget (round-1 lesson: stay well under 4 MB): 2M hT + 256K E/F + 512K
// mask = 2.75 MB.

#define B_DIM 8
#define N_DIM 2048
#define C_IN  128
#define C_OUT 64
#define NROWS (B_DIM * N_DIM)   // 16384
#define LOG2E 1.4426950408889634f

namespace cg = cooperative_groups;

typedef short bf16x8 __attribute__((ext_vector_type(8)));
typedef short bf16x4 __attribute__((ext_vector_type(4)));
typedef float f32x4  __attribute__((ext_vector_type(4)));

static __device__ __forceinline__ short f2bf(float x) {
    __hip_bfloat16 b = __float2bfloat16(x);
    return *reinterpret_cast<short*>(&b);
}

// ==================== FUSED cooperative kernel ====================
__global__ __launch_bounds__(512, 4) void gat_fused(
    const float* __restrict__ inp,   // [B,N,C_IN]
    const float* __restrict__ W,     // [C_IN,C_OUT]
    const float* __restrict__ a,     // [2*C_OUT]
    const float* __restrict__ adj,   // [N,N]
    __hip_bfloat16* __restrict__ hT, // [B][C_OUT][N] bf16
    float* __restrict__ E1, float* __restrict__ F1,   // [B*N]
    float* __restrict__ E2, float* __restrict__ F2,   // [B*N]
    unsigned long long* __restrict__ mask,  // [N][N/64], diag folded in
    float* __restrict__ out)                // [B,N,C_OUT]
{
    // LDS union: phase A uses [0]=Wl(32K), [1]=tr(64x33x4=8.4K);
    // phase C uses both as the 2x32K double buffer / epilogue accL.
    __shared__ __align__(16) char smem[2][32768];
    __shared__ float lred[8][2][16];
    __shared__ float a1l[C_OUT], a2l[C_OUT];

    const int tid  = threadIdx.x;
    const int wave = tid >> 6;             // 0..7
    const int lane = tid & 63;
    const int tb   = blockIdx.x;           // 0..511

    // ---------------- Phase A: projection (32 rows) + mask (4 rows) ----------------
    {
        float* Wl = (float*)smem[0];                   // flat [c*64+f] (r9 layout)
        float (*tr)[33] = (float(*)[33])smem[1];       // [64][33]

        for (int t = tid; t < C_IN * C_OUT / 4; t += 512)
            ((float4*)Wl)[t] = ((const float4*)W)[t];
        if (tid < C_OUT) {
            a1l[tid] = a[tid];
            a2l[tid] = a[C_OUT + tid];
        }
        __syncthreads();

        const int i0 = tb * 32;            // global row base (never crosses batch)
        const int b  = i0 >> 11;
        const int il = i0 & (N_DIM - 1);
        const int rl = wave * 4;           // this wave's 4 rows (same shape as r9)

        const float* __restrict__ x0 = inp + (size_t)(i0 + rl) * C_IN;
        const float* __restrict__ x1 = x0 + C_IN;
        const float* __restrict__ x2 = x1 + C_IN;
        const float* __restrict__ x3 = x2 + C_IN;
        float h0 = 0.f, h1 = 0.f, h2 = 0.f, h3 = 0.f;
#pragma unroll 4
        for (int c = 0; c < C_IN; c += 4) {
            const float4 a0 = *(const float4*)(x0 + c);
            const float4 a1v = *(const float4*)(x1 + c);
            const float4 a2v = *(const float4*)(x2 + c);
            const float4 a3v = *(const float4*)(x3 + c);
#pragma unroll
            for (int cc = 0; cc < 4; ++cc) {
                const float w_ = Wl[(c + cc) * C_OUT + lane];
                const float e0 = (cc==0)?a0.x:(cc==1)?a0.y:(cc==2)?a0.z:a0.w;
                const float e1 = (cc==0)?a1v.x:(cc==1)?a1v.y:(cc==2)?a1v.z:a1v.w;
                const float e2 = (cc==0)?a2v.x:(cc==1)?a2v.y:(cc==2)?a2v.z:a2v.w;
                const float e3 = (cc==0)?a3v.x:(cc==1)?a3v.y:(cc==2)?a3v.z:a3v.w;
                h0 = fmaf(e0, w_, h0);
                h1 = fmaf(e1, w_, h1);
                h2 = fmaf(e2, w_, h2);
                h3 = fmaf(e3, w_, h3);
            }
        }
        tr[lane][rl + 0] = h0;             // stride 33: conflict-free
        tr[lane][rl + 1] = h1;
        tr[lane][rl + 2] = h2;
        tr[lane][rl + 3] = h3;

        float hv[4] = {h0, h1, h2, h3};
#pragma unroll
        for (int k = 0; k < 4; ++k) {
            float p1 = hv[k] * a1l[lane];
            float p2 = hv[k] * a2l[lane];
#pragma unroll
            for (int off = 32; off; off >>= 1) {
                p1 += __shfl_xor(p1, off, 64);
                p2 += __shfl_xor(p2, off, 64);
            }
            if (lane == 0) {
                const float z1 = p1 * LOG2E;
                const float z2 = p2 * LOG2E;
                const int r = i0 + rl + k;
                E1[r] = exp2f(z1);
                F1[r] = exp2f(0.01f * z1);
                E2[r] = exp2f(z2);
                F2[r] = exp2f(0.01f * z2);
            }
        }
        __syncthreads();

        // hT[b][f][il+ro4..+4): tid -> f = tid>>3, ro4 = (tid&7)*4
        {
            const int f   = tid >> 3;
            const int ro4 = (tid & 7) * 4;
            bf16x4 v;
            v[0] = f2bf(tr[f][ro4 + 0]);
            v[1] = f2bf(tr[f][ro4 + 1]);
            v[2] = f2bf(tr[f][ro4 + 2]);
            v[3] = f2bf(tr[f][ro4 + 3]);
            *(bf16x4*)(hT + ((size_t)b * C_OUT + f) * N_DIM + il + ro4) = v;
        }

        // mask-pack: 4 adj rows per block
#pragma unroll
        for (int r = 0; r < 4; ++r) {
            const int i = tb * 4 + r;
            const float* __restrict__ arow = adj + (size_t)i * N_DIM;
#pragma unroll
            for (int it = 0; it < 4; ++it) {
                const int j = it * 512 + wave * 64 + lane;
                const bool conn = (arow[j] > 0.f) || (j == i);   // diag folded in
                const unsigned long long bm = __ballot(conn);
                if (lane == 0) mask[(size_t)i * (N_DIM / 64) + (j >> 6)] = bm;
            }
        }
    }

    // ---------------- Phase B: grid-wide barrier (cross-XCD visibility) ----------------
    __threadfence();                       // release: flush L2 writes device-scope
    cg::this_grid().sync();
    __threadfence();                       // acquire: invalidate stale lines

    // ---------------- Phase C: MFMA attention (r9 verbatim) ----------------
    {
        const int b  = tb >> 6;            // 64 row-tiles of 32 per batch
        const int i0 = (tb & 63) * 32;
        const int mloc = lane & 15;
        const int quad = lane >> 4;
        const int igA  = i0 + mloc;
        const int igB  = i0 + 16 + mloc;

        const float E1A = E1[(size_t)b * N_DIM + igA];
        const float F1A = F1[(size_t)b * N_DIM + igA];
        const float E1B = E1[(size_t)b * N_DIM + igB];
        const float F1B = F1[(size_t)b * N_DIM + igB];
        const float* __restrict__ E2b = E2 + (size_t)b * N_DIM;
        const float* __restrict__ F2b = F2 + (size_t)b * N_DIM;
        const uint8_t* __restrict__ mA = (const uint8_t*)mask + (size_t)igA * (N_DIM / 8);
        const uint8_t* __restrict__ mBp = (const uint8_t*)mask + (size_t)igB * (N_DIM / 8);
        const char* __restrict__ hTb = (const char*)(hT + (size_t)b * C_OUT * N_DIM);

        f32x4 aA0 = {0,0,0,0}, aA1 = {0,0,0,0}, aA2 = {0,0,0,0}, aA3 = {0,0,0,0};
        f32x4 aB0 = {0,0,0,0}, aB1 = {0,0,0,0}, aB2 = {0,0,0,0}, aB3 = {0,0,0,0};
        f32x4 lA = {0,0,0,0}, lB = {0,0,0,0};
        const bf16x8 ones = {(short)0x3F80, (short)0x3F80, (short)0x3F80, (short)0x3F80,
                             (short)0x3F80, (short)0x3F80, (short)0x3F80, (short)0x3F80};

        const int bjl = wave * 32 + quad * 8;
        const int cA  = bjl >> 3;

        auto compute_chunk = [&](int jc, const char* buf) {
            const int jg = jc * 256 + bjl;
            const unsigned mbA = mA[jg >> 3];
            const unsigned mbB = mBp[jg >> 3];
            const f32x4 eA = *(const f32x4*)(E2b + jg);
            const f32x4 eB = *(const f32x4*)(E2b + jg + 4);
            const f32x4 fA = *(const f32x4*)(F2b + jg);
            const f32x4 fB = *(const f32x4*)(F2b + jg + 4);
            bf16x8 pf0, pf1;
#pragma unroll
            for (int t = 0; t < 8; ++t) {
                const float ev = (t < 4 ? eA[t] : eB[t - 4]);
                const float fv = (t < 4 ? fA[t] : fB[t - 4]);
                float p0 = fmaxf(E1A * ev, F1A * fv);
                p0 = ((mbA >> t) & 1u) ? p0 : 0.f;
                pf0[t] = f2bf(p0);
                float p1 = fmaxf(E1B * ev, F1B * fv);
                p1 = ((mbB >> t) & 1u) ? p1 : 0.f;
                pf1[t] = f2bf(p1);
            }
            lA = __builtin_amdgcn_mfma_f32_16x16x32_bf16(pf0, ones, lA, 0, 0, 0);
            lB = __builtin_amdgcn_mfma_f32_16x16x32_bf16(pf1, ones, lB, 0, 0, 0);
#pragma unroll
            for (int nb = 0; nb < 4; ++nb) {
                const int f  = nb * 16 + mloc;
                const int cS = (cA & 16) | ((cA ^ (f & 15)) & 15);
                const bf16x8 bF = *(const bf16x8*)(buf + (f * 32 + cS) * 16);
                if (nb == 0) { aA0 = __builtin_amdgcn_mfma_f32_16x16x32_bf16(pf0, bF, aA0, 0, 0, 0);
                               aB0 = __builtin_amdgcn_mfma_f32_16x16x32_bf16(pf1, bF, aB0, 0, 0, 0); }
                if (nb == 1) { aA1 = __builtin_amdgcn_mfma_f32_16x16x32_bf16(pf0, bF, aA1, 0, 0, 0);
                               aB1 = __builtin_amdgcn_mfma_f32_16x16x32_bf16(pf1, bF, aB1, 0, 0, 0); }
                if (nb == 2) { aA2 = __builtin_amdgcn_mfma_f32_16x16x32_bf16(pf0, bF, aA2, 0, 0, 0);
                               aB2 = __builtin_amdgcn_mfma_f32_16x16x32_bf16(pf1, bF, aB2, 0, 0, 0); }
                if (nb == 3) { aA3 = __builtin_amdgcn_mfma_f32_16x16x32_bf16(pf0, bF, aA3, 0, 0, 0);
                               aB3 = __builtin_amdgcn_mfma_f32_16x16x32_bf16(pf1, bF, aB3, 0, 0, 0); }
            }
        };

        for (int jc = 0; jc < 8; ++jc) {
            __syncthreads();
#pragma unroll
            for (int q = 0; q < 4; ++q) {
                const int p = (wave * 4 + q) * 64 + lane;
                const int f  = p >> 5;
                const int cs = p & 31;
                const int c  = (cs & 16) | ((cs ^ (f & 15)) & 15);
                const char* gp = hTb + ((size_t)f * N_DIM + jc * 256) * 2 + c * 16;
                char* lp = smem[jc & 1] + (wave * 4 + q) * 1024;
                __builtin_amdgcn_global_load_lds(
                    (const __attribute__((address_space(1))) void*)gp,
                    (__attribute__((address_space(3))) void*)lp, 16, 0, 0);
            }
            if (jc > 0) compute_chunk(jc - 1, smem[(jc - 1) & 1]);
        }
        __syncthreads();
        compute_chunk(7, smem[1]);
        __syncthreads();

        if (mloc == 0) {
#pragma unroll
            for (int reg = 0; reg < 4; ++reg) {
                lred[wave][0][quad * 4 + reg] = lA[reg];
                lred[wave][1][quad * 4 + reg] = lB[reg];
            }
        }

        float* accL = (float*)smem;
#pragma unroll
        for (int reg = 0; reg < 4; ++reg) {
            const int r = quad * 4 + reg;
            float* pa = accL + ((wave * 2 + 0) * 16 + r) * 64 + mloc;
            float* pb = accL + ((wave * 2 + 1) * 16 + r) * 64 + mloc;
            pa[ 0] = aA0[reg]; pa[16] = aA1[reg]; pa[32] = aA2[reg]; pa[48] = aA3[reg];
            pb[ 0] = aB0[reg]; pb[16] = aB1[reg]; pb[32] = aB2[reg]; pb[48] = aB3[reg];
        }
        __syncthreads();

        float* __restrict__ ob = out + ((size_t)b * N_DIM + i0) * C_OUT;
#pragma unroll
        for (int e = tid; e < 32 * C_OUT; e += 512) {
            const int R  = e >> 6;
            const int hf = R >> 4;
            const int r  = R & 15;
            const int fc = e & 63;
            float s = 0.f, ls = 0.f;
#pragma unroll
            for (int w = 0; w < 8; ++w) {
                s  += accL[((w * 2 + hf) * 16 + r) * 64 + fc];
                ls += lred[w][hf][r];
            }
            ob[e] = s / ls;
        }
    }
}

// ==================== Fallback: r9 two-kernel path ====================
__global__ __launch_bounds__(256) void gat_prep(
    const float* __restrict__ inp, const float* __restrict__ W,
    const float* __restrict__ a, const float* __restrict__ adj,
    __hip_bfloat16* __restrict__ hT,
    float* __restrict__ E1, float* __restrict__ F1,
    float* __restrict__ E2, float* __restrict__ F2,
    unsigned long long* __restrict__ mask)
{
    __shared__ float Wl[C_IN * C_OUT];
    __shared__ float a1l[C_OUT], a2l[C_OUT];
    __shared__ float tr[C_OUT][17];

    if (blockIdx.x >= 1024) {
        const int i    = blockIdx.x - 1024;
        const int wave = threadIdx.x >> 6;
        const int lane = threadIdx.x & 63;
        const float* __restrict__ arow = adj + (size_t)i * N_DIM;
#pragma unroll
        for (int it = 0; it < 8; ++it) {
            const int j = wave * 512 + it * 64 + lane;
            const bool conn = (arow[j] > 0.f) || (j == i);
            const unsigned long long bm = __ballot(conn);
            if (lane == 0) mask[(size_t)i * (N_DIM / 64) + (j >> 6)] = bm;
        }
        return;
    }
    {
        const float4* Wv = (const float4*)W;
        float4* Wd = (float4*)Wl;
        for (int t = threadIdx.x; t < C_IN * C_OUT / 4; t += 256) Wd[t] = Wv[t];
        if (threadIdx.x < C_OUT) {
            a1l[threadIdx.x] = a[threadIdx.x];
            a2l[threadIdx.x] = a[C_OUT + threadIdx.x];
        }
    }
    __syncthreads();
    const int wave = threadIdx.x >> 6;
    const int lane = threadIdx.x & 63;
    const int i0 = blockIdx.x * 16;
    const int b  = i0 >> 11;
    const int il = i0 & (N_DIM - 1);
    const int rl = wave * 4;
    const float* __restrict__ x0 = inp + (size_t)(i0 + rl) * C_IN;
    const float* __restrict__ x1 = x0 + C_IN;
    const float* __restrict__ x2 = x1 + C_IN;
    const float* __restrict__ x3 = x2 + C_IN;
    float h0 = 0.f, h1 = 0.f, h2 = 0.f, h3 = 0.f;
#pragma unroll 4
    for (int c = 0; c < C_IN; c += 4) {
        const float4 a0 = *(const float4*)(x0 + c);
        const float4 a1v = *(const float4*)(x1 + c);
        const float4 a2v = *(const float4*)(x2 + c);
        const float4 a3v = *(const float4*)(x3 + c);
#pragma unroll
        for (int cc = 0; cc < 4; ++cc) {
            const float w_ = Wl[(c + cc) * C_OUT + lane];
            const float e0 = (cc==0)?a0.x:(cc==1)?a0.y:(cc==2)?a0.z:a0.w;
            const float e1 = (cc==0)?a1v.x:(cc==1)?a1v.y:(cc==2)?a1v.z:a1v.w;
            const float e2 = (cc==0)?a2v.x:(cc==1)?a2v.y:(cc==2)?a2v.z:a2v.w;
            const float e3 = (cc==0)?a3v.x:(cc==1)?a3v.y:(cc==2)?a3v.z:a3v.w;
            h0 = fmaf(e0, w_, h0); h1 = fmaf(e1, w_, h1);
            h2 = fmaf(e2, w_, h2); h3 = fmaf(e3, w_, h3);
        }
    }
    tr[lane][rl + 0] = h0; tr[lane][rl + 1] = h1;
    tr[lane][rl + 2] = h2; tr[lane][rl + 3] = h3;
    float hv[4] = {h0, h1, h2, h3};
#pragma unroll
    for (int k = 0; k < 4; ++k) {
        float p1 = hv[k] * a1l[lane];
        float p2 = hv[k] * a2l[lane];
#pragma unroll
        for (int off = 32; off; off >>= 1) {
            p1 += __shfl_xor(p1, off, 64);
            p2 += __shfl_xor(p2, off, 64);
        }
        if (lane == 0) {
            const float z1 = p1 * LOG2E;
            const float z2 = p2 * LOG2E;
            const int r = i0 + rl + k;
            E1[r] = exp2f(z1); F1[r] = exp2f(0.01f * z1);
            E2[r] = exp2f(z2); F2[r] = exp2f(0.01f * z2);
        }
    }
    __syncthreads();
    const int f   = threadIdx.x >> 2;
    const int ro4 = (threadIdx.x & 3) * 4;
    bf16x4 v;
    v[0] = f2bf(tr[f][ro4 + 0]); v[1] = f2bf(tr[f][ro4 + 1]);
    v[2] = f2bf(tr[f][ro4 + 2]); v[3] = f2bf(tr[f][ro4 + 3]);
    *(bf16x4*)(hT + ((size_t)b * C_OUT + f) * N_DIM + il + ro4) = v;
}

__global__ __launch_bounds__(512, 4) void gat_attn(
    const __hip_bfloat16* __restrict__ hT,
    const float* __restrict__ E1, const float* __restrict__ F1,
    const float* __restrict__ E2, const float* __restrict__ F2,
    const unsigned long long* __restrict__ mask,
    float* __restrict__ out)
{
    __shared__ __align__(16) char smem[2][32768];
    __shared__ float lred[8][2][16];
    const int wave = threadIdx.x >> 6;
    const int lane = threadIdx.x & 63;
    const int tb = blockIdx.x;
    const int b  = tb >> 6;
    const int i0 = (tb & 63) * 32;
    const int mloc = lane & 15;
    const int quad = lane >> 4;
    const int igA  = i0 + mloc;
    const int igB  = i0 + 16 + mloc;
    const float E1A = E1[(size_t)b * N_DIM + igA];
    const float F1A = F1[(size_t)b * N_DIM + igA];
    const float E1B = E1[(size_t)b * N_DIM + igB];
    const float F1B = F1[(size_t)b * N_DIM + igB];
    const float* __restrict__ E2b = E2 + (size_t)b * N_DIM;
    const float* __restrict__ F2b = F2 + (size_t)b * N_DIM;
    const uint8_t* __restrict__ mA = (const uint8_t*)mask + (size_t)igA * (N_DIM / 8);
    const uint8_t* __restrict__ mBp = (const uint8_t*)mask + (size_t)igB * (N_DIM / 8);
    const char* __restrict__ hTb = (const char*)(hT + (size_t)b * C_OUT * N_DIM);
    f32x4 aA0 = {0,0,0,0}, aA1 = {0,0,0,0}, aA2 = {0,0,0,0}, aA3 = {0,0,0,0};
    f32x4 aB0 = {0,0,0,0}, aB1 = {0,0,0,0}, aB2 = {0,0,0,0}, aB3 = {0,0,0,0};
    f32x4 lA = {0,0,0,0}, lB = {0,0,0,0};
    const bf16x8 ones = {(short)0x3F80, (short)0x3F80, (short)0x3F80, (short)0x3F80,
                         (short)0x3F80, (short)0x3F80, (short)0x3F80, (short)0x3F80};
    const int bjl = wave * 32 + quad * 8;
    const int cA  = bjl >> 3;
    auto compute_chunk = [&](int jc, const char* buf) {
        const int jg = jc * 256 + bjl;
        const unsigned mbA = mA[jg >> 3];
        const unsigned mbB = mBp[jg >> 3];
        const f32x4 eA = *(const f32x4*)(E2b + jg);
        const f32x4 eB = *(const f32x4*)(E2b + jg + 4);
        const f32x4 fA = *(const f32x4*)(F2b + jg);
        const f32x4 fB = *(const f32x4*)(F2b + jg + 4);
        bf16x8 pf0, pf1;
#pragma unroll
        for (int t = 0; t < 8; ++t) {
            const float ev = (t < 4 ? eA[t] : eB[t - 4]);
            const float fv = (t < 4 ? fA[t] : fB[t - 4]);
            float p0 = fmaxf(E1A * ev, F1A * fv);
            p0 = ((mbA >> t) & 1u) ? p0 : 0.f;
            pf0[t] = f2bf(p0);
            float p1 = fmaxf(E1B * ev, F1B * fv);
            p1 = ((mbB >> t) & 1u) ? p1 : 0.f;
            pf1[t] = f2bf(p1);
        }
        lA = __builtin_amdgcn_mfma_f32_16x16x32_bf16(pf0, ones, lA, 0, 0, 0);
        lB = __builtin_amdgcn_mfma_f32_16x16x32_bf16(pf1, ones, lB, 0, 0, 0);
#pragma unroll
        for (int nb = 0; nb < 4; ++nb) {
            const int f  = nb * 16 + mloc;
            const int cS = (cA & 16) | ((cA ^ (f & 15)) & 15);
            const bf16x8 bF = *(const bf16x8*)(buf + (f * 32 + cS) * 16);
            if (nb == 0) { aA0 = __builtin_amdgcn_mfma_f32_16x16x32_bf16(pf0, bF, aA0, 0, 0, 0);
                           aB0 = __builtin_amdgcn_mfma_f32_16x16x32_bf16(pf1, bF, aB0, 0, 0, 0); }
            if (nb == 1) { aA1 = __builtin_amdgcn_mfma_f32_16x16x32_bf16(pf0, bF, aA1, 0, 0, 0);
                           aB1 = __builtin_amdgcn_mfma_f32_16x16x32_bf16(pf1, bF, aB1, 0, 0, 0); }
            if (nb == 2) { aA2 = __builtin_amdgcn_mfma_f32_16x16x32_bf16(pf0, bF, aA2, 0, 0, 0);
                           aB2 = __builtin_amdgcn_mfma_f32_16x16x32_bf16(pf1, bF, aB2, 0, 0, 0); }
            if (nb == 3) { aA3 = __builtin_amdgcn_mfma_f32_16x16x32_bf16(pf0, bF, aA3, 0, 0, 0);
                           aB3 = __builtin_amdgcn_mfma_f32_16x16x32_bf16(pf1, bF, aB3, 0, 0, 0); }
        }
    };
    for (int jc = 0; jc < 8; ++jc) {
        __syncthreads();
#pragma unroll
        for (int q = 0; q < 4; ++q) {
            const int p = (wave * 4 + q) * 64 + lane;
            const int f  = p >> 5;
            const int cs = p & 31;
            const int c  = (cs & 16) | ((cs ^ (f & 15)) & 15);
            const char* gp = hTb + ((size_t)f * N_DIM + jc * 256) * 2 + c * 16;
            char* lp = smem[jc & 1] + (wave * 4 + q) * 1024;
            __builtin_amdgcn_global_load_lds(
                (const __attribute__((address_space(1))) void*)gp,
                (__attribute__((address_space(3))) void*)lp, 16, 0, 0);
        }
        if (jc > 0) compute_chunk(jc - 1, smem[(jc - 1) & 1]);
    }
    __syncthreads();
    compute_chunk(7, smem[1]);
    __syncthreads();
    if (mloc == 0) {
#pragma unroll
        for (int reg = 0; reg < 4; ++reg) {
            lred[wave][0][quad * 4 + reg] = lA[reg];
            lred[wave][1][quad * 4 + reg] = lB[reg];
        }
    }
    float* accL = (float*)smem;
#pragma unroll
    for (int reg = 0; reg < 4; ++reg) {
        const int r = quad * 4 + reg;
        float* pa = accL + ((wave * 2 + 0) * 16 + r) * 64 + mloc;
        float* pb = accL + ((wave * 2 + 1) * 16 + r) * 64 + mloc;
        pa[ 0] = aA0[reg]; pa[16] = aA1[reg]; pa[32] = aA2[reg]; pa[48] = aA3[reg];
        pb[ 0] = aB0[reg]; pb[16] = aB1[reg]; pb[32] = aB2[reg]; pb[48] = aB3[reg];
    }
    __syncthreads();
    float* __restrict__ ob = out + ((size_t)b * N_DIM + i0) * C_OUT;
#pragma unroll
    for (int e = threadIdx.x; e < 32 * C_OUT; e += 512) {
        const int R  = e >> 6;
        const int hf = R >> 4;
        const int r  = R & 15;
        const int fc = e & 63;
        float s = 0.f, ls = 0.f;
#pragma unroll
        for (int w = 0; w < 8; ++w) {
            s  += accL[((w * 2 + hf) * 16 + r) * 64 + fc];
            ls += lred[w][hf][r];
        }
        ob[e] = s / ls;
    }
}

extern "C" void kernel_launch(void* const* d_in, const int* in_sizes, int n_in,
                              void* d_out, int out_size, void* d_ws, size_t ws_size,
                              hipStream_t stream) {
    const float* inp = (const float*)d_in[0];   // [8,2048,128]
    const float* adj = (const float*)d_in[1];   // [2048,2048]
    const float* W   = (const float*)d_in[2];   // [128,64]
    const float* a   = (const float*)d_in[3];   // [128]
    float* out = (float*)d_out;                 // [8,2048,64]

    // ws layout (2.75 MB total):
    char* ws = (char*)d_ws;
    __hip_bfloat16* hT = (__hip_bfloat16*)ws;                       // 2 MB
    float* E1 = (float*)(ws + (size_t)2 * 1024 * 1024);             // 64 KB
    float* F1 = E1 + NROWS;                                         // 64 KB
    float* E2 = F1 + NROWS;                                         // 64 KB
    float* F2 = E2 + NROWS;                                         // 64 KB
    unsigned long long* mask = (unsigned long long*)(F2 + NROWS);   // 512 KB

    void* args[] = {(void*)&inp, (void*)&W, (void*)&a, (void*)&adj, (void*)&hT,
                    (void*)&E1, (void*)&F1, (void*)&E2, (void*)&F2,
                    (void*)&mask, (void*)&out};
    hipError_t err = hipLaunchCooperativeKernel((const void*)gat_fused,
                                                dim3(512), dim3(512),
                                                args, 0, stream);
    if (err != hipSuccess) {
        // fallback: proven r9 two-kernel path (deterministic per-process)
        gat_prep<<<1024 + N_DIM, 256, 0, stream>>>(inp, W, a, adj, hT, E1, F1, E2, F2, mask);
        gat_attn<<<NROWS / 32, 512, 0, stream>>>(hT, E1, F1, E2, F2, mask, out);
    }
}

// Round 12
// 112.983 us; speedup vs baseline: 2.8519x; 2.8519x over previous
//
#include <hip/hip_runtime.h>
#include <hip/hip_bf16.h>
#include <cstddef>
#include <cstdint>

// GAT layer: B=8, N=2048, C_IN=128, C_OUT=64, fp32 in/out.
//
// Rank-1 scores: e[b,i,j] = lrelu(s1[b,i] + s2[b,j]); mask = adj>0 | diag.
// Unnormalized softmax (shift-invariant; e bounded => exp fits fp32).
// lrelu(z)=max(z,0.01z) and exp2 monotone => p = max(E1*E2, F1*F2) with
// E=exp2(z·log2e), F=exp2(0.01z·log2e) per row — inner loop has NO exp.
// l row-sum via extra MFMA against all-ones B fragment.
//
// ROUND-12: REVERT to round-9 verbatim (session best, 112.4 us).
// r10 (prep W b128 layout) was neutral (+1.1); r11 (cooperative fusion) was a
// catastrophic regression (322 us — cg::this_grid().sync() is a software
// spin barrier across XCDs, ~200 us at 512 blocks; dispatch boundary it
// replaced costs only ~5 us). Session accounting: our kernels ~15 us chip
// time; the rest of the timed window is harness reset (268 MB ws poison at
// 76% HBM peak = 44 us + input restores) + fixed dispatch overhead.
//
// K1 (gat_prep, 3072 blocks): [0,1024) projection (h=inp@W, W in LDS, hT bf16
//     [B][C_OUT][N] via LDS transpose, E1/F1/E2/F2); [1024,3072) adj->bitmask.
// K2 (gat_attn, 512 blocks x 512 thr): 8 waves = 8 j-eighths, each wave does
//     BOTH 16-row i-subtiles sharing one B-frag ds_read; j in 256-chunks; hT
//     chunk DMA'd to LDS (global_load_lds, double-buffered, XOR-swizzled
//     conflict-free ds_read_b128); 16x16x32 bf16 MFMA; l fused via ones-MFMA.
//
// ws budget (round-1 lesson: stay well under 4 MB): 2M hT + 256K E/F + 512K
// mask = 2.75 MB.

#define B_DIM 8
#define N_DIM 2048
#define C_IN  128
#define C_OUT 64
#define NROWS (B_DIM * N_DIM)   // 16384
#define LOG2E 1.4426950408889634f

typedef short bf16x8 __attribute__((ext_vector_type(8)));
typedef short bf16x4 __attribute__((ext_vector_type(4)));
typedef float f32x4  __attribute__((ext_vector_type(4)));

static __device__ __forceinline__ short f2bf(float x) {
    __hip_bfloat16 b = __float2bfloat16(x);
    return *reinterpret_cast<short*>(&b);
}

// ---------------- Kernel 1: fused projection + mask-pack ----------------
__global__ __launch_bounds__(256) void gat_prep(
    const float* __restrict__ inp,   // [B,N,C_IN]
    const float* __restrict__ W,     // [C_IN,C_OUT]
    const float* __restrict__ a,     // [2*C_OUT]
    const float* __restrict__ adj,   // [N,N]
    __hip_bfloat16* __restrict__ hT, // [B][C_OUT][N] bf16
    float* __restrict__ E1, float* __restrict__ F1,   // [B*N]
    float* __restrict__ E2, float* __restrict__ F2,   // [B*N]
    unsigned long long* __restrict__ mask)  // [N][N/64], diag folded in
{
    __shared__ float Wl[C_IN * C_OUT];     // 32 KB
    __shared__ float a1l[C_OUT], a2l[C_OUT];
    __shared__ float tr[C_OUT][17];        // 16-row transpose buffer, padded

    if (blockIdx.x >= 1024) {
        // ---- mask-pack block: one adj row ----
        const int i    = blockIdx.x - 1024;
        const int wave = threadIdx.x >> 6;
        const int lane = threadIdx.x & 63;
        const float* __restrict__ arow = adj + (size_t)i * N_DIM;
#pragma unroll
        for (int it = 0; it < 8; ++it) {
            const int j = wave * 512 + it * 64 + lane;
            const bool conn = (arow[j] > 0.f) || (j == i);   // diag folded in
            const unsigned long long bm = __ballot(conn);
            if (lane == 0) mask[(size_t)i * (N_DIM / 64) + (j >> 6)] = bm;
        }
        return;
    }

    // ---- projection block: 16 rows ----
    {
        const float4* Wv = (const float4*)W;
        float4* Wd = (float4*)Wl;
        for (int t = threadIdx.x; t < C_IN * C_OUT / 4; t += 256) Wd[t] = Wv[t];
        if (threadIdx.x < C_OUT) {
            a1l[threadIdx.x] = a[threadIdx.x];
            a2l[threadIdx.x] = a[C_OUT + threadIdx.x];
        }
    }
    __syncthreads();

    const int wave = threadIdx.x >> 6;
    const int lane = threadIdx.x & 63;
    const int i0 = blockIdx.x * 16;        // 16 rows per block (never crosses batch)
    const int b  = i0 >> 11;
    const int il = i0 & (N_DIM - 1);
    const int rl = wave * 4;               // this wave's 4 rows

    const float* __restrict__ x0 = inp + (size_t)(i0 + rl) * C_IN;
    const float* __restrict__ x1 = x0 + C_IN;
    const float* __restrict__ x2 = x1 + C_IN;
    const float* __restrict__ x3 = x2 + C_IN;
    float h0 = 0.f, h1 = 0.f, h2 = 0.f, h3 = 0.f;
#pragma unroll 4
    for (int c = 0; c < C_IN; c += 4) {
        const float4 a0 = *(const float4*)(x0 + c);
        const float4 a1 = *(const float4*)(x1 + c);
        const float4 a2 = *(const float4*)(x2 + c);
        const float4 a3 = *(const float4*)(x3 + c);
#pragma unroll
        for (int cc = 0; cc < 4; ++cc) {
            const float w_ = Wl[(c + cc) * C_OUT + lane];
            const float e0 = (cc==0)?a0.x:(cc==1)?a0.y:(cc==2)?a0.z:a0.w;
            const float e1 = (cc==0)?a1.x:(cc==1)?a1.y:(cc==2)?a1.z:a1.w;
            const float e2 = (cc==0)?a2.x:(cc==1)?a2.y:(cc==2)?a2.z:a2.w;
            const float e3 = (cc==0)?a3.x:(cc==1)?a3.y:(cc==2)?a3.z:a3.w;
            h0 = fmaf(e0, w_, h0);
            h1 = fmaf(e1, w_, h1);
            h2 = fmaf(e2, w_, h2);
            h3 = fmaf(e3, w_, h3);
        }
    }
    tr[lane][rl + 0] = h0;                 // stride 17: conflict-free
    tr[lane][rl + 1] = h1;
    tr[lane][rl + 2] = h2;
    tr[lane][rl + 3] = h3;

    float hv[4] = {h0, h1, h2, h3};
#pragma unroll
    for (int k = 0; k < 4; ++k) {
        float p1 = hv[k] * a1l[lane];
        float p2 = hv[k] * a2l[lane];
#pragma unroll
        for (int off = 32; off; off >>= 1) {
            p1 += __shfl_xor(p1, off, 64);
            p2 += __shfl_xor(p2, off, 64);
        }
        if (lane == 0) {
            const float z1 = p1 * LOG2E;   // exp(x) = exp2(x*log2e)
            const float z2 = p2 * LOG2E;
            const int r = i0 + rl + k;
            E1[r] = exp2f(z1);
            F1[r] = exp2f(0.01f * z1);
            E2[r] = exp2f(z2);
            F2[r] = exp2f(0.01f * z2);
        }
    }
    __syncthreads();

    // hT[b][f][il+ro4..+4): thread t -> f = t>>2, ro4 = (t&3)*4
    const int f   = threadIdx.x >> 2;
    const int ro4 = (threadIdx.x & 3) * 4;
    bf16x4 v;
    v[0] = f2bf(tr[f][ro4 + 0]);
    v[1] = f2bf(tr[f][ro4 + 1]);
    v[2] = f2bf(tr[f][ro4 + 2]);
    v[3] = f2bf(tr[f][ro4 + 3]);
    *(bf16x4*)(hT + ((size_t)b * C_OUT + f) * N_DIM + il + ro4) = v;
}

// ---------------- Kernel 2: MFMA attention, dbuf LDS, shared B-frags ----------------
// 8 waves = 8 j-eighths (32 j each per 256-chunk); each wave computes BOTH
// 16-row i-subtiles, sharing one B-fragment ds_read per (nb).
__global__ __launch_bounds__(512, 4) void gat_attn(
    const __hip_bfloat16* __restrict__ hT,        // [B][C_OUT][N]
    const float* __restrict__ E1, const float* __restrict__ F1,
    const float* __restrict__ E2, const float* __restrict__ F2,
    const unsigned long long* __restrict__ mask,  // [N][N/64]
    float* __restrict__ out)                      // [B,N,C_OUT]
{
    __shared__ __align__(16) char smem[2][32768]; // double buffer / epilogue accL (64 KB)
    __shared__ float lred[8][2][16];

    const int wave = threadIdx.x >> 6;     // 0..7 = j-eighth
    const int lane = threadIdx.x & 63;
    const int tb = blockIdx.x;             // 0..511
    const int b  = tb >> 6;                // 64 row-tiles of 32 per batch
    const int i0 = (tb & 63) * 32;
    const int mloc = lane & 15;
    const int quad = lane >> 4;
    const int igA  = i0 + mloc;            // subtile A row (local to batch)
    const int igB  = i0 + 16 + mloc;       // subtile B row

    const float E1A = E1[(size_t)b * N_DIM + igA];
    const float F1A = F1[(size_t)b * N_DIM + igA];
    const float E1B = E1[(size_t)b * N_DIM + igB];
    const float F1B = F1[(size_t)b * N_DIM + igB];
    const float* __restrict__ E2b = E2 + (size_t)b * N_DIM;
    const float* __restrict__ F2b = F2 + (size_t)b * N_DIM;
    const uint8_t* __restrict__ mA = (const uint8_t*)mask + (size_t)igA * (N_DIM / 8);
    const uint8_t* __restrict__ mBp = (const uint8_t*)mask + (size_t)igB * (N_DIM / 8);
    const char* __restrict__ hTb = (const char*)(hT + (size_t)b * C_OUT * N_DIM);

    f32x4 aA0 = {0,0,0,0}, aA1 = {0,0,0,0}, aA2 = {0,0,0,0}, aA3 = {0,0,0,0};
    f32x4 aB0 = {0,0,0,0}, aB1 = {0,0,0,0}, aB2 = {0,0,0,0}, aB3 = {0,0,0,0};
    f32x4 lA = {0,0,0,0}, lB = {0,0,0,0};  // l row-sums via ones-MFMA
    const bf16x8 ones = {(short)0x3F80, (short)0x3F80, (short)0x3F80, (short)0x3F80,
                         (short)0x3F80, (short)0x3F80, (short)0x3F80, (short)0x3F80};

    const int bjl = wave * 32 + quad * 8;  // this lane's within-chunk j base
    const int cA  = bjl >> 3;              // 16B-chunk idx 0..31

    // compute one 256-j chunk from LDS buffer `buf`
    auto compute_chunk = [&](int jc, const char* buf) {
        const int jg = jc * 256 + bjl;
        const unsigned mbA = mA[jg >> 3];
        const unsigned mbB = mBp[jg >> 3];
        const f32x4 eA = *(const f32x4*)(E2b + jg);
        const f32x4 eB = *(const f32x4*)(E2b + jg + 4);
        const f32x4 fA = *(const f32x4*)(F2b + jg);
        const f32x4 fB = *(const f32x4*)(F2b + jg + 4);
        bf16x8 pf0, pf1;
#pragma unroll
        for (int t = 0; t < 8; ++t) {
            const float ev = (t < 4 ? eA[t] : eB[t - 4]);
            const float fv = (t < 4 ? fA[t] : fB[t - 4]);
            float p0 = fmaxf(E1A * ev, F1A * fv);      // = exp2(lrelu(zA))
            p0 = ((mbA >> t) & 1u) ? p0 : 0.f;
            pf0[t] = f2bf(p0);
            float p1 = fmaxf(E1B * ev, F1B * fv);
            p1 = ((mbB >> t) & 1u) ? p1 : 0.f;
            pf1[t] = f2bf(p1);
        }
        lA = __builtin_amdgcn_mfma_f32_16x16x32_bf16(pf0, ones, lA, 0, 0, 0);
        lB = __builtin_amdgcn_mfma_f32_16x16x32_bf16(pf1, ones, lB, 0, 0, 0);
#pragma unroll
        for (int nb = 0; nb < 4; ++nb) {
            const int f  = nb * 16 + mloc;
            const int cS = (cA & 16) | ((cA ^ (f & 15)) & 15);
            const bf16x8 bF = *(const bf16x8*)(buf + (f * 32 + cS) * 16);  // shared by both subtiles
            if (nb == 0) { aA0 = __builtin_amdgcn_mfma_f32_16x16x32_bf16(pf0, bF, aA0, 0, 0, 0);
                           aB0 = __builtin_amdgcn_mfma_f32_16x16x32_bf16(pf1, bF, aB0, 0, 0, 0); }
            if (nb == 1) { aA1 = __builtin_amdgcn_mfma_f32_16x16x32_bf16(pf0, bF, aA1, 0, 0, 0);
                           aB1 = __builtin_amdgcn_mfma_f32_16x16x32_bf16(pf1, bF, aB1, 0, 0, 0); }
            if (nb == 2) { aA2 = __builtin_amdgcn_mfma_f32_16x16x32_bf16(pf0, bF, aA2, 0, 0, 0);
                           aB2 = __builtin_amdgcn_mfma_f32_16x16x32_bf16(pf1, bF, aB2, 0, 0, 0); }
            if (nb == 3) { aA3 = __builtin_amdgcn_mfma_f32_16x16x32_bf16(pf0, bF, aA3, 0, 0, 0);
                           aB3 = __builtin_amdgcn_mfma_f32_16x16x32_bf16(pf1, bF, aB3, 0, 0, 0); }
        }
    };

    for (int jc = 0; jc < 8; ++jc) {
        __syncthreads();   // readers of this buffer (chunk jc-2) done; DMA jc-1 drained
        // DMA chunk jc into smem[jc&1] (swizzled), 4 instr/wave
#pragma unroll
        for (int q = 0; q < 4; ++q) {
            const int p = (wave * 4 + q) * 64 + lane;       // 0..2047
            const int f  = p >> 5;
            const int cs = p & 31;
            const int c  = (cs & 16) | ((cs ^ (f & 15)) & 15);
            const char* gp = hTb + ((size_t)f * N_DIM + jc * 256) * 2 + c * 16;
            char* lp = smem[jc & 1] + (wave * 4 + q) * 1024; // + lane*16 implicit
            __builtin_amdgcn_global_load_lds(
                (const __attribute__((address_space(1))) void*)gp,
                (__attribute__((address_space(3))) void*)lp, 16, 0, 0);
        }
        if (jc > 0) compute_chunk(jc - 1, smem[(jc - 1) & 1]);
    }
    __syncthreads();       // drains DMA of chunk 7
    compute_chunk(7, smem[1]);
    __syncthreads();       // safe to reuse smem as accL

    // l: lX[reg] = row-sum for row quad*4+reg (all 16 cols identical)
    if (mloc == 0) {
#pragma unroll
        for (int reg = 0; reg < 4; ++reg) {
            lred[wave][0][quad * 4 + reg] = lA[reg];
            lred[wave][1][quad * 4 + reg] = lB[reg];
        }
    }

    // C/D layout: row r = quad*4+reg, col f = nb*16+mloc
    float* accL = (float*)smem;            // [8 waves][2 halves][16 rows][64 f] = 64 KB
#pragma unroll
    for (int reg = 0; reg < 4; ++reg) {
        const int r = quad * 4 + reg;
        float* pa = accL + ((wave * 2 + 0) * 16 + r) * 64 + mloc;
        float* pb = accL + ((wave * 2 + 1) * 16 + r) * 64 + mloc;
        pa[ 0] = aA0[reg]; pa[16] = aA1[reg]; pa[32] = aA2[reg]; pa[48] = aA3[reg];
        pb[ 0] = aB0[reg]; pb[16] = aB1[reg]; pb[32] = aB2[reg]; pb[48] = aB3[reg];
    }
    __syncthreads();

    float* __restrict__ ob = out + ((size_t)b * N_DIM + i0) * C_OUT;
#pragma unroll
    for (int e = threadIdx.x; e < 32 * C_OUT; e += 512) {
        const int R  = e >> 6;             // output row 0..31
        const int hf = R >> 4;             // which i-subtile
        const int r  = R & 15;
        const int fc = e & 63;
        float s = 0.f, ls = 0.f;
#pragma unroll
        for (int w = 0; w < 8; ++w) {
            s  += accL[((w * 2 + hf) * 16 + r) * 64 + fc];
            ls += lred[w][hf][r];
        }
        ob[e] = s / ls;
    }
}

extern "C" void kernel_launch(void* const* d_in, const int* in_sizes, int n_in,
                              void* d_out, int out_size, void* d_ws, size_t ws_size,
                              hipStream_t stream) {
    const float* inp = (const float*)d_in[0];   // [8,2048,128]
    const float* adj = (const float*)d_in[1];   // [2048,2048]
    const float* W   = (const float*)d_in[2];   // [128,64]
    const float* a   = (const float*)d_in[3];   // [128]
    float* out = (float*)d_out;                 // [8,2048,64]

    // ws layout (2.75 MB total):
    char* ws = (char*)d_ws;
    __hip_bfloat16* hT = (__hip_bfloat16*)ws;                       // 2 MB
    float* E1 = (float*)(ws + (size_t)2 * 1024 * 1024);             // 64 KB
    float* F1 = E1 + NROWS;                                         // 64 KB
    float* E2 = F1 + NROWS;                                         // 64 KB
    float* F2 = E2 + NROWS;                                         // 64 KB
    unsigned long long* mask = (unsigned long long*)(F2 + NROWS);   // 512 KB

    gat_prep<<<1024 + N_DIM, 256, 0, stream>>>(inp, W, a, adj, hT, E1, F1, E2, F2, mask);
    gat_attn<<<NROWS / 32, 512, 0, stream>>>(hT, E1, F1, E2, F2, mask, out);
}